// Round 4
// baseline (4776.263 us; speedup 1.0000x reference)
//
#include <hip/hip_runtime.h>
#include <cstdint>
#include <cstddef>

#define NUSERS 200000
#define NENT   500000
#define NEDGE  2000000
#define NNZV   2000000
#define DIM    64

// ---- float <-> order-preserving unsigned key (for atomicMax on floats) ----
// memset(0) is a valid "-inf" init: every real float's key is > 0.
__device__ __forceinline__ unsigned fkey(float f) {
    unsigned b = __float_as_uint(f);
    return (b & 0x80000000u) ? ~b : (b | 0x80000000u);
}
__device__ __forceinline__ float finv(unsigned k) {
    unsigned b = (k & 0x80000000u) ? (k & 0x7FFFFFFFu) : ~k;
    return __uint_as_float(b);
}

// ---- K1: wave-per-edge  w1[e] = dot(ent[tail], rel[etype-1]) / 8 ; segment max ----
__global__ void edge_w_max_kernel(const float* __restrict__ ent,
                                  const float* __restrict__ rel,
                                  const int* __restrict__ head,
                                  const int* __restrict__ tail,
                                  const int* __restrict__ etype,
                                  float* __restrict__ w,
                                  unsigned* __restrict__ mseg,
                                  int E)
{
    int idx  = blockIdx.x * blockDim.x + threadIdx.x;
    int e    = idx >> 6;
    int lane = idx & 63;
    if (e >= E) return;
    int t = tail[e];
    int r = etype[e] - 1;
    float v = ent[(size_t)t * DIM + lane] * rel[(size_t)r * DIM + lane];
#pragma unroll
    for (int off = 32; off; off >>= 1) v += __shfl_xor(v, off);
    if (lane == 0) {
        float ww = v * 0.125f;
        w[e] = ww;
        atomicMax(&mseg[head[e]], fkey(ww));
    }
}

// ---- K4: wave-per-nnz  att = dot(inter[it] * usr[u], ent[item]) ; segment max ----
__global__ void user_att_max_kernel(const float* __restrict__ ent,
                                    const float* __restrict__ usr,
                                    const float* __restrict__ inter,
                                    const int* __restrict__ uidx,
                                    const int* __restrict__ iidx,
                                    const int* __restrict__ itype,
                                    float* __restrict__ att,
                                    unsigned* __restrict__ mseg,
                                    int E)
{
    int idx  = blockIdx.x * blockDim.x + threadIdx.x;
    int e    = idx >> 6;
    int lane = idx & 63;
    if (e >= E) return;
    int u  = uidx[e];
    int it = itype[e];
    int im = iidx[e];
    float v = inter[(size_t)it * DIM + lane] * usr[(size_t)u * DIM + lane] *
              ent[(size_t)im * DIM + lane];
#pragma unroll
    for (int off = 32; off; off >>= 1) v += __shfl_xor(v, off);
    if (lane == 0) {
        att[e] = v;
        atomicMax(&mseg[u], fkey(v));
    }
}

// ---- K2/K5: thread-per-edge  s[seg] += exp(w - m[seg]) ----
__global__ void seg_expsum_kernel(const float* __restrict__ w,
                                  const int* __restrict__ idx,
                                  const unsigned* __restrict__ mseg,
                                  float* __restrict__ sseg,
                                  int E)
{
    int e = blockIdx.x * blockDim.x + threadIdx.x;
    if (e >= E) return;
    int s = idx[e];
    atomicAdd(&sseg[s], expf(w[e] - finv(mseg[s])));
}

// ---- K3/K6: wave-per-edge  agg[seg] += src[srcidx] * (exp(w-m)/s) ----
__global__ void edge_scatter_kernel(const float* __restrict__ src,
                                    const float* __restrict__ w,
                                    const int* __restrict__ segidx,
                                    const int* __restrict__ srcidx,
                                    const unsigned* __restrict__ mseg,
                                    const float* __restrict__ sseg,
                                    float* __restrict__ agg,
                                    int E)
{
    int idx  = blockIdx.x * blockDim.x + threadIdx.x;
    int e    = idx >> 6;
    int lane = idx & 63;
    if (e >= E) return;
    int sg = segidx[e];
    int sr = srcidx[e];
    float ww = expf(w[e] - finv(mseg[sg])) / sseg[sg];
    float val = src[(size_t)sr * DIM + lane] * ww;
    atomicAdd(&agg[(size_t)sg * DIM + lane], val);
}

// ---- K7/K8: wave-per-row  l2-normalize agg in place, accumulate into out ----
__global__ void norm_res_kernel(float* __restrict__ agg,
                                float* __restrict__ out,
                                int N)
{
    int idx  = blockIdx.x * blockDim.x + threadIdx.x;
    int row  = idx >> 6;
    int lane = idx & 63;
    if (row >= N) return;
    float v  = agg[(size_t)row * DIM + lane];
    float ss = v * v;
#pragma unroll
    for (int off = 32; off; off >>= 1) ss += __shfl_xor(ss, off);
    float inv = 1.0f / fmaxf(sqrtf(ss), 1e-12f);
    float nv  = v * inv;
    agg[(size_t)row * DIM + lane] = nv;
    out[(size_t)row * DIM + lane] += nv;
}

extern "C" void kernel_launch(void* const* d_in, const int* in_sizes, int n_in,
                              void* d_out, int out_size, void* d_ws, size_t ws_size,
                              hipStream_t stream)
{
    const float* user_emb     = (const float*)d_in[0];
    const float* entity_emb   = (const float*)d_in[1];
    const float* interact_emb = (const float*)d_in[2];
    const float* relation_emb = (const float*)d_in[3];
    const int*   edge_index   = (const int*)d_in[4];
    const int*   edge_type    = (const int*)d_in[5];
    const int*   user_index   = (const int*)d_in[6];
    const int*   item_index   = (const int*)d_in[7];
    const int*   interact_tp  = (const int*)d_in[8];
    const int* head = edge_index;            // edge_index[0, :]
    const int* tail = edge_index + NEDGE;    // edge_index[1, :]

    // ---- workspace layout ----
    char* ws = (char*)d_ws;
    size_t o = 0;
    const size_t ENT_BYTES = (size_t)NENT * DIM * sizeof(float);
    const size_t USR_BYTES = (size_t)NUSERS * DIM * sizeof(float);
    float*    entA  = (float*)(ws + o); o += ENT_BYTES;
    float*    entB  = (float*)(ws + o); o += ENT_BYTES;
    float*    usrA  = (float*)(ws + o); o += USR_BYTES;
    float*    usrB  = (float*)(ws + o); o += USR_BYTES;
    float*    w1    = (float*)(ws + o); o += (size_t)NEDGE * sizeof(float);
    float*    att   = (float*)(ws + o); o += (size_t)NNZV * sizeof(float);
    unsigned* m_ent = (unsigned*)(ws + o); o += (size_t)NENT * sizeof(unsigned);
    float*    s_ent = (float*)(ws + o); o += (size_t)NENT * sizeof(float);
    unsigned* m_usr = (unsigned*)(ws + o); o += (size_t)NUSERS * sizeof(unsigned);
    float*    s_usr = (float*)(ws + o); o += (size_t)NUSERS * sizeof(float);
    if (ws_size < o) return;  // workspace too small — fail visibly

    float* out_ent = (float*)d_out;
    float* out_usr = out_ent + (size_t)NENT * DIM;

    // residual accumulators start as the input embeddings
    hipMemcpyAsync(out_ent, entity_emb, ENT_BYTES, hipMemcpyDeviceToDevice, stream);
    hipMemcpyAsync(out_usr, user_emb, USR_BYTES, hipMemcpyDeviceToDevice, stream);

    const int BLK = 256;
    const int edge_wave_blocks = (int)(((size_t)NEDGE * 64 + BLK - 1) / BLK);
    const int edge_thr_blocks  = (NEDGE + BLK - 1) / BLK;
    const int nnz_wave_blocks  = (int)(((size_t)NNZV * 64 + BLK - 1) / BLK);
    const int nnz_thr_blocks   = (NNZV + BLK - 1) / BLK;
    const int ent_row_blocks   = (int)(((size_t)NENT * 64 + BLK - 1) / BLK);
    const int usr_row_blocks   = (int)(((size_t)NUSERS * 64 + BLK - 1) / BLK);

    const float* ecur = entity_emb;
    const float* ucur = user_emb;
    float* eaggs[2] = {entA, entB};
    float* uaggs[2] = {usrA, usrB};

    for (int hop = 0; hop < 2; ++hop) {
        float* ea = eaggs[hop];
        float* ua = uaggs[hop];
        hipMemsetAsync(ea, 0, ENT_BYTES, stream);
        hipMemsetAsync(ua, 0, USR_BYTES, stream);
        hipMemsetAsync(m_ent, 0, (size_t)NENT * 4, stream);   // key 0 == -inf
        hipMemsetAsync(s_ent, 0, (size_t)NENT * 4, stream);
        hipMemsetAsync(m_usr, 0, (size_t)NUSERS * 4, stream);
        hipMemsetAsync(s_usr, 0, (size_t)NUSERS * 4, stream);

        // --- KG entity aggregation ---
        edge_w_max_kernel<<<edge_wave_blocks, BLK, 0, stream>>>(
            ecur, relation_emb, head, tail, edge_type, w1, m_ent, NEDGE);
        seg_expsum_kernel<<<edge_thr_blocks, BLK, 0, stream>>>(
            w1, head, m_ent, s_ent, NEDGE);
        edge_scatter_kernel<<<edge_wave_blocks, BLK, 0, stream>>>(
            ecur, w1, head, tail, m_ent, s_ent, ea, NEDGE);

        // --- user aggregation (attention) ---
        user_att_max_kernel<<<nnz_wave_blocks, BLK, 0, stream>>>(
            ecur, ucur, interact_emb, user_index, item_index, interact_tp,
            att, m_usr, NNZV);
        seg_expsum_kernel<<<nnz_thr_blocks, BLK, 0, stream>>>(
            att, user_index, m_usr, s_usr, NNZV);
        edge_scatter_kernel<<<nnz_wave_blocks, BLK, 0, stream>>>(
            ecur, att, user_index, item_index, m_usr, s_usr, ua, NNZV);

        // --- normalize + residual ---
        norm_res_kernel<<<ent_row_blocks, BLK, 0, stream>>>(ea, out_ent, NENT);
        norm_res_kernel<<<usr_row_blocks, BLK, 0, stream>>>(ua, out_usr, NUSERS);

        ecur = ea;
        ucur = ua;
    }
}